// Round 9
// baseline (784.381 us; speedup 1.0000x reference)
//
#include <hip/hip_runtime.h>

#define T_   2
#define IN_  6
#define DIM_ 36
#define LIN_ 54
#define OUT_ 18
#define BN_EPS 1e-5f

#define WSH_   7        // bucket width = 128 dst nodes
#define WMSK_  127
#define CAP_   2560     // per-bucket capacity (mean 2046, 11 sigma headroom)
#define TILE_  6144     // edges per binsort block
#define NBMAX_ 1024     // max buckets supported by in-LDS scan

__device__ __forceinline__ unsigned short f2bf(float f) {
    unsigned u = __float_as_uint(f);
    unsigned r = (u + 0x7FFFu + ((u >> 16) & 1u)) >> 16;    // RNE
    return (unsigned short)r;
}
__device__ __forceinline__ float bf2f(unsigned short h) {
    return __uint_as_float(((unsigned)h) << 16);
}

// ===========================================================================
// binsort_k: bin edges by dst bucket with LDS staging; coalesced packed
// writes (src 17b | dstoff 7b). Grid covers tc transforms: lt = bid/gbin.
// ===========================================================================
__global__ __launch_bounds__(256) void binsort_k(
    const int* __restrict__ ei, int t0, int gbin,
    int* __restrict__ bcnt, int* __restrict__ bbuf, int ne, int nb)
{
    __shared__ int cntl[NBMAX_], cursl[NBMAX_], gbasel[NBMAX_];
    __shared__ int aux[256];
    __shared__ int sortedl[TILE_];

    const int tid  = threadIdx.x;
    const int lt   = blockIdx.x / gbin;
    const int tile = blockIdx.x % gbin;
    const int base = tile * TILE_;
    const int cnt_e = min(TILE_, ne - base);
    const int* srcp = ei + (size_t)(t0 + lt) * 2 * ne;
    const int* dstp = srcp + ne;
    int* bcnt_t = bcnt + (size_t)lt * nb;

    for (int i = tid; i < NBMAX_; i += 256) cntl[i] = 0;
    __syncthreads();

    for (int i = tid; i < cnt_e; i += 256)
        atomicAdd(&cntl[dstp[base + i] >> WSH_], 1);
    __syncthreads();

    int t4 = tid * 4;
    int c0 = cntl[t4+0], c1 = cntl[t4+1], c2 = cntl[t4+2], c3 = cntl[t4+3];
    int lsum = c0 + c1 + c2 + c3;
    aux[tid] = lsum;
    __syncthreads();
    for (int off = 1; off < 256; off <<= 1) {
        int v = (tid >= off) ? aux[tid - off] : 0;
        __syncthreads();
        aux[tid] += v;
        __syncthreads();
    }
    int eb = aux[tid] - lsum;
    cursl[t4+0] = eb;
    cursl[t4+1] = eb + c0;
    cursl[t4+2] = eb + c0 + c1;
    cursl[t4+3] = eb + c0 + c1 + c2;
    __syncthreads();

    for (int b = tid; b < nb; b += 256) {
        int c = cntl[b];
        gbasel[b] = c ? atomicAdd(&bcnt_t[b], c) : 0;
    }
    __syncthreads();

    for (int i = tid; i < cnt_e; i += 256) {
        int s = srcp[base + i], d = dstp[base + i];
        int p = atomicAdd(&cursl[d >> WSH_], 1);
        sortedl[p] = s | ((d & WMSK_) << 17);
    }
    __syncthreads();

    int wv = tid >> 6, ln = tid & 63;
    for (int b = wv; b < nb; b += 4) {
        int c = cntl[b];
        if (!c) continue;
        int lb = cursl[b] - c;
        int gb = gbasel[b];
        size_t ga = ((size_t)lt * nb + b) * CAP_ + gb;
        for (int i = ln; i < c; i += 64)
            if (gb + i < CAP_) bbuf[ga + i] = sortedl[lb + i];
    }
}

// ===========================================================================
// csrify_k: one block per (t,bucket): sort bucket by dst node in LDS, write
// back coalesced (unpacked src), emit rp (global into bbuf) and deg.
// ===========================================================================
__global__ __launch_bounds__(256) void csrify_k(
    const int* __restrict__ bcnt, int* __restrict__ bbuf,
    int* __restrict__ rp, int* __restrict__ deg, int n, int nb)
{
    __shared__ int ent[CAP_], srt[CAP_];
    __shared__ int cnt[128], cur[128], sc[128];
    const int b = blockIdx.x, tid = threadIdx.x;
    const int blocal = b % nb, lt = b / nb;
    int c = min(bcnt[b], CAP_);
    int* seg = bbuf + (size_t)b * CAP_;

    for (int i = tid; i < c; i += 256) ent[i] = seg[i];
    if (tid < 128) cnt[tid] = 0;
    __syncthreads();
    for (int i = tid; i < c; i += 256)
        atomicAdd(&cnt[(ent[i] >> 17) & WMSK_], 1);
    __syncthreads();
    if (tid < 128) sc[tid] = cnt[tid];
    __syncthreads();
    for (int off = 1; off < 128; off <<= 1) {
        int v = (tid >= off && tid < 128) ? sc[tid - off] : 0;
        __syncthreads();
        if (tid < 128) sc[tid] += v;
        __syncthreads();
    }
    int node0 = blocal << WSH_;
    if (tid < 128) {
        int excl = sc[tid] - cnt[tid];
        cur[tid] = excl;
        if (node0 + tid < n) {
            rp[(size_t)lt * n + node0 + tid]  = b * CAP_ + excl;
            deg[(size_t)lt * n + node0 + tid] = cnt[tid];
        }
    }
    __syncthreads();
    for (int i = tid; i < c; i += 256) {
        int v = ent[i];
        int p = atomicAdd(&cur[(v >> 17) & WMSK_], 1);
        srt[p] = v & 0x1FFFF;
    }
    __syncthreads();
    for (int i = tid; i < c; i += 256) seg[i] = srt[i];
}

// ===========================================================================
// gather_k (conv1 only, D=6): agg[i] = x[i] + sum_{nbr} x[nbr], fp32.
// ===========================================================================
template<int D>
__global__ __launch_bounds__(576) void gather_k(
        const float* __restrict__ hbase, size_t hstride,
        const int* __restrict__ rp, const int* __restrict__ deg,
        const int* __restrict__ csr, float* __restrict__ agg,
        size_t astride, int n)
{
    const int NPB = 576 / D;
    const int slot = blockIdx.y;
    const float* h = hbase + (size_t)slot * hstride;
    int g = blockIdx.x * NPB + threadIdx.x / D;
    int lane = threadIdx.x % D;
    if (g >= n) return;
    int lo = rp[(size_t)slot * n + g], hi = lo + deg[(size_t)slot * n + g];
    float a0 = h[(size_t)g * D + lane], a1 = 0.f, a2 = 0.f, a3 = 0.f;
    int e = lo;
    for (; e + 3 < hi; e += 4) {
        int s0 = csr[e], s1 = csr[e + 1], s2 = csr[e + 2], s3 = csr[e + 3];
        a0 += h[(size_t)s0 * D + lane];
        a1 += h[(size_t)s1 * D + lane];
        a2 += h[(size_t)s2 * D + lane];
        a3 += h[(size_t)s3 * D + lane];
    }
    for (; e < hi; ++e) a0 += h[(size_t)csr[e] * D + lane];
    agg[(size_t)slot * astride + (size_t)g * D + lane] = (a0 + a1) + (a2 + a3);
}

// ===========================================================================
// node6_k (conv1 MLP): hin = agg (no BN before conv1); y = relu(Wa hin+ba);
// out = relu(Wb y+bb); bf16 z out; per-block BN stat row. Grid (gn, tc).
// ===========================================================================
__global__ __launch_bounds__(256) void node6_k(
    const float* __restrict__ agg, size_t astride,
    const float* __restrict__ wAb, const float* __restrict__ bAb,
    const float* __restrict__ wBb, const float* __restrict__ bBb,
    int t0,
    unsigned short* __restrict__ zho, size_t zstride,
    float* __restrict__ bstats, int gn, int n)
{
    __shared__ float sstat[4][2 * DIM_];
    const int slot = blockIdx.y;
    const int t = t0 + slot;
    const float* wa = wAb + (size_t)t * DIM_ * IN_;
    const float* ba = bAb + (size_t)t * DIM_;
    const float* wb = wBb + (size_t)t * DIM_ * DIM_;
    const float* bb = bBb + (size_t)t * DIM_;

    int node = blockIdx.x * 256 + threadIdx.x;
    bool active = node < n;

    float hin[IN_];
    if (active) {
        const float2* ar2 = reinterpret_cast<const float2*>(
                agg + (size_t)slot * astride + (size_t)node * IN_);
        float2 v0 = ar2[0], v1 = ar2[1], v2 = ar2[2];
        hin[0] = v0.x; hin[1] = v0.y; hin[2] = v1.x;
        hin[3] = v1.y; hin[4] = v2.x; hin[5] = v2.y;
    } else {
        #pragma unroll
        for (int k = 0; k < IN_; ++k) hin[k] = 0.f;
    }

    float y[DIM_];
    #pragma unroll
    for (int j = 0; j < DIM_; ++j) {
        float acc = ba[j];
        #pragma unroll
        for (int k = 0; k < IN_; ++k) acc = fmaf(wa[j * IN_ + k], hin[k], acc);
        y[j] = fmaxf(acc, 0.f);
    }
    float out[DIM_];
    #pragma unroll
    for (int j = 0; j < DIM_; ++j) {
        float acc = bb[j];
        #pragma unroll
        for (int k = 0; k < DIM_; ++k) acc = fmaf(wb[j * DIM_ + k], y[k], acc);
        out[j] = active ? fmaxf(acc, 0.f) : 0.f;
    }

    if (active) {
        unsigned short* zr = zho + (size_t)slot * zstride + (size_t)node * DIM_;
        #pragma unroll
        for (int j = 0; j < DIM_; ++j) zr[j] = f2bf(out[j]);
    }

    int wid = threadIdx.x >> 6, lane = threadIdx.x & 63;
    #pragma unroll
    for (int j = 0; j < DIM_; ++j) {
        float s = out[j], sq = out[j] * out[j];
        for (int off = 32; off; off >>= 1) {
            s  += __shfl_down(s,  off);
            sq += __shfl_down(sq, off);
        }
        if (lane == 0) { sstat[wid][j] = s; sstat[wid][DIM_ + j] = sq; }
    }
    __syncthreads();
    if (threadIdx.x < 2 * DIM_) {
        float s = sstat[0][threadIdx.x] + sstat[1][threadIdx.x]
                + sstat[2][threadIdx.x] + sstat[3][threadIdx.x];
        bstats[((size_t)slot * gn + blockIdx.x) * (2 * DIM_) + threadIdx.x] = s;
    }
}

// ===========================================================================
// conv36f_k: FUSED gather + BN-affine + 2-layer MLP + BN-stats for convs 2,3.
// 576 threads = 16 nodes x 36 lanes; 8 sub-tiles -> 128 nodes/block.
// Gather phase: feature-per-lane register accumulation from bf16 rows
//   hin = a.(self+sum) + (1+deg).b2  -> LDS hin[16][37]
// MLP phase: same threads as (node, j): y from waT (transposed, conflict-
//   free), transpose via LDS yt, out from wbT; bf16 z out; stat row/block.
// ===========================================================================
__global__ __launch_bounds__(576) void conv36f_k(
    const unsigned short* __restrict__ zh, size_t zhstride,
    const int* __restrict__ rp, const int* __restrict__ deg,
    const int* __restrict__ csr,
    const float* __restrict__ coef,
    const float* __restrict__ wAb, const float* __restrict__ bAb,
    const float* __restrict__ wBb, const float* __restrict__ bBb,
    int t0,
    unsigned short* __restrict__ zho,
    float* __restrict__ bstats, int gb, int n)
{
    __shared__ float waT[DIM_ * DIM_], wbT[DIM_ * DIM_];
    __shared__ float sba[DIM_], sbb[DIM_], sca[DIM_], scb2[DIM_];
    __shared__ float hin[16][DIM_ + 1], yt[16][DIM_ + 1];
    __shared__ float st[16][2 * DIM_ + 2];

    const int tid = threadIdx.x;
    const int slot = blockIdx.y;
    const int t = t0 + slot;
    const float* wa = wAb + (size_t)t * DIM_ * DIM_;
    const float* wb = wBb + (size_t)t * DIM_ * DIM_;

    for (int i = tid; i < DIM_ * DIM_; i += 576) {
        int j = i / DIM_, k = i - j * DIM_;
        waT[k * DIM_ + j] = wa[i];
        wbT[k * DIM_ + j] = wb[i];
    }
    if (tid < DIM_) {
        sba[tid]  = bAb[(size_t)t * DIM_ + tid];
        sbb[tid]  = bBb[(size_t)t * DIM_ + tid];
        sca[tid]  = coef[(size_t)slot * 2 * DIM_ + tid];
        scb2[tid] = coef[(size_t)slot * 2 * DIM_ + DIM_ + tid];
    }
    __syncthreads();

    const int group = tid / DIM_, lane = tid - group * DIM_;
    const unsigned short* zhs = zh + (size_t)slot * zhstride;
    float s_acc = 0.f, sq_acc = 0.f;

    #pragma unroll 1
    for (int tile = 0; tile < 8; ++tile) {
        int g = blockIdx.x * 128 + tile * 16 + group;
        float av = 0.f, dsc = 0.f;
        if (g < n) {
            size_t off = (size_t)slot * n + g;
            int lo = rp[off], d = deg[off];
            int hi = lo + d;
            float a0 = bf2f(zhs[(size_t)g * DIM_ + lane]);
            float a1 = 0.f, a2 = 0.f, a3 = 0.f;
            int e = lo;
            for (; e + 3 < hi; e += 4) {
                int s0 = csr[e], s1 = csr[e+1], s2 = csr[e+2], s3 = csr[e+3];
                a0 += bf2f(zhs[(size_t)s0 * DIM_ + lane]);
                a1 += bf2f(zhs[(size_t)s1 * DIM_ + lane]);
                a2 += bf2f(zhs[(size_t)s2 * DIM_ + lane]);
                a3 += bf2f(zhs[(size_t)s3 * DIM_ + lane]);
            }
            for (; e < hi; ++e) a0 += bf2f(zhs[(size_t)csr[e] * DIM_ + lane]);
            av = (a0 + a1) + (a2 + a3);
            dsc = 1.f + (float)d;
        }
        hin[group][lane] = sca[lane] * av + dsc * scb2[lane];
        __syncthreads();

        float acc = sba[lane];
        #pragma unroll
        for (int k = 0; k < DIM_; ++k)
            acc = fmaf(waT[k * DIM_ + lane], hin[group][k], acc);
        yt[group][lane] = fmaxf(acc, 0.f);
        __syncthreads();

        float acc2 = sbb[lane];
        #pragma unroll
        for (int k = 0; k < DIM_; ++k)
            acc2 = fmaf(wbT[k * DIM_ + lane], yt[group][k], acc2);
        float o = (g < n) ? fmaxf(acc2, 0.f) : 0.f;
        if (g < n)
            zho[(size_t)slot * zhstride + (size_t)g * DIM_ + lane] = f2bf(o);
        s_acc += o; sq_acc += o * o;
        __syncthreads();
    }

    st[group][lane] = s_acc;
    st[group][DIM_ + lane] = sq_acc;
    __syncthreads();
    if (tid < 2 * DIM_) {
        float s = 0.f;
        #pragma unroll
        for (int q = 0; q < 16; ++q) s += st[q][tid];
        bstats[((size_t)slot * gb + blockIdx.x) * (2 * DIM_) + tid] = s;
    }
}

// ===========================================================================
// bnfin_k: reduce nrows stat rows -> fused affine coef {a, b2}. Grid (tc).
// ===========================================================================
__global__ __launch_bounds__(288) void bnfin_k(
    const float* __restrict__ bstats, int nrows, int rstride,
    const float* __restrict__ bng, const float* __restrict__ bnb,
    int t0, int c, float* __restrict__ coef, float inv_n)
{
    __shared__ float part[4][2 * DIM_];
    const int slot = blockIdx.x;
    const int t = t0 + slot;
    int tid = threadIdx.x;
    int col = tid % (2 * DIM_), quarter = tid / (2 * DIM_);
    const float* bs = bstats + (size_t)slot * rstride * (2 * DIM_);
    float s = 0.f;
    for (int i = quarter; i < nrows; i += 4) s += bs[(size_t)i * (2 * DIM_) + col];
    part[quarter][col] = s;
    __syncthreads();
    if (tid < 2 * DIM_)
        part[0][tid] = part[0][tid] + part[1][tid] + part[2][tid] + part[3][tid];
    __syncthreads();
    if (tid < DIM_) {
        float mean = part[0][tid] * inv_n;
        float var  = part[0][DIM_ + tid] * inv_n - mean * mean;
        float aa   = bng[((size_t)t * 3 + c) * DIM_ + tid] / sqrtf(var + BN_EPS);
        coef[(size_t)slot * 2 * DIM_ + tid]        = aa;
        coef[(size_t)slot * 2 * DIM_ + DIM_ + tid] = bnb[((size_t)t * 3 + c) * DIM_ + tid] - aa * mean;
    }
}

// ===========================================================================
// pool_k: per-graph mean pool over bf16 z (batch sorted), conv-3 coef.
// ===========================================================================
__global__ __launch_bounds__(288) void pool_k(
    const unsigned short* __restrict__ zh, size_t zstride,
    const float* __restrict__ coef,
    const int* __restrict__ batch, int t0,
    float* __restrict__ emb, int n)
{
    __shared__ int slo, shi;
    __shared__ float spool[288];
    const int slot = blockIdx.y;
    const int t = t0 + slot;
    const int* bt = batch + (size_t)t * n;
    const unsigned short* zt = zh + (size_t)slot * zstride;
    const float* ca  = coef + (size_t)slot * 2 * DIM_;
    const float* cb2 = ca + DIM_;

    int g = blockIdx.x;
    int tid = threadIdx.x;
    if (tid == 0) {
        int lo = 0, hi = n;
        while (lo < hi) { int m = (lo + hi) >> 1; if (bt[m] < g) lo = m + 1; else hi = m; }
        slo = lo;
        int lo2 = lo, hi2 = n;
        while (lo2 < hi2) { int m = (lo2 + hi2) >> 1; if (bt[m] < g + 1) lo2 = m + 1; else hi2 = m; }
        shi = lo2;
    }
    __syncthreads();
    int lo = slo, hi = shi;
    int f = tid % DIM_, j = tid / DIM_;
    float acc = 0.f;
    for (int i = lo + j; i < hi; i += 8) acc += bf2f(zt[(size_t)i * DIM_ + f]);
    spool[tid] = acc;
    __syncthreads();
    if (tid < DIM_) {
        float s = 0.f;
        #pragma unroll
        for (int jj = 0; jj < 8; ++jj) s += spool[f + DIM_ * jj];
        int cnt = hi - lo;
        float val = 0.f;
        if (cnt > 0) val = ca[f] * (s / (float)cnt) + cb2[f];
        emb[(size_t)g * (T_ * DIM_) + t * DIM_ + f] = val;
    }
}

// ===========================================================================
// head_k: one 64-thread block per graph, layers staged through LDS.
// ===========================================================================
__global__ __launch_bounds__(64) void head_k(
    const float* __restrict__ emb,
    const float* __restrict__ hw1, const float* __restrict__ hb1,
    const float* __restrict__ hw2, const float* __restrict__ hb2,
    const float* __restrict__ hw3, const float* __restrict__ hb3,
    float* __restrict__ out, int ng)
{
    const int EMB = T_ * DIM_;
    int g = blockIdx.x;
    if (g >= ng) return;
    __shared__ float se[EMB], st1[LIN_], st2[OUT_];
    int tid = threadIdx.x;
    for (int i = tid; i < EMB; i += 64) se[i] = emb[(size_t)g * EMB + i];
    __syncthreads();
    if (tid < LIN_) {
        float acc = hb1[tid];
        #pragma unroll
        for (int k = 0; k < EMB; ++k) acc = fmaf(hw1[tid * EMB + k], se[k], acc);
        st1[tid] = fmaxf(acc, 0.f);
    }
    __syncthreads();
    if (tid < OUT_) {
        float acc = hb2[tid];
        #pragma unroll
        for (int k = 0; k < LIN_; ++k) acc = fmaf(hw2[tid * LIN_ + k], st1[k], acc);
        st2[tid] = fmaxf(acc, 0.f);
    }
    __syncthreads();
    if (tid == 0) {
        float acc = hb3[0];
        #pragma unroll
        for (int k = 0; k < OUT_; ++k) acc = fmaf(hw3[k], st2[k], acc);
        out[g] = 1.f / (1.f + expf(-acc));
    }
}

// ===========================================================================
extern "C" void kernel_launch(void* const* d_in, const int* in_sizes, int n_in,
                              void* d_out, int out_size, void* d_ws, size_t ws_size,
                              hipStream_t stream)
{
    const float* x     = (const float*)d_in[0];
    const int*   ei    = (const int*)d_in[1];
    const int*   batch = (const int*)d_in[2];
    const float* wA[3] = {(const float*)d_in[3], (const float*)d_in[7], (const float*)d_in[11]};
    const float* bA[3] = {(const float*)d_in[4], (const float*)d_in[8], (const float*)d_in[12]};
    const float* wB[3] = {(const float*)d_in[5], (const float*)d_in[9], (const float*)d_in[13]};
    const float* bB[3] = {(const float*)d_in[6], (const float*)d_in[10], (const float*)d_in[14]};
    const float* bng = (const float*)d_in[15];
    const float* bnb = (const float*)d_in[16];
    const float* hw1 = (const float*)d_in[17];
    const float* hb1 = (const float*)d_in[18];
    const float* hw2 = (const float*)d_in[19];
    const float* hb2 = (const float*)d_in[20];
    const float* hw3 = (const float*)d_in[21];
    const float* hb3 = (const float*)d_in[22];

    const int N = in_sizes[2] / T_;
    const int E = in_sizes[1] / (2 * T_);
    const int G = out_size;
    const int NB = (N + WMSK_) / 128;         // dst buckets
    const int gn  = (N + 255) / 256;          // node6 blocks / stat rows
    const int gb  = (N + 127) / 128;          // conv36f blocks / stat rows
    const float inv_n = 1.0f / (float)N;
    const int gbin = (E + TILE_ - 1) / TILE_;

    const size_t bufN = (size_t)N * DIM_;     // elements per (slot) z buffer
    auto need = [&](int tc) -> size_t {
        size_t f = (size_t)tc * N * IN_                        // agg (fp32)
                 + (size_t)tc * gb * 2 * DIM_                  // bstats
                 + (size_t)tc * 2 * DIM_                       // coef
                 + (size_t)G * T_ * DIM_;                      // emb
        size_t hs = 2 * (size_t)tc * bufN;                     // zhA+zhB (ushort)
        size_t ii = (size_t)tc * NB + 2 * (size_t)tc * N + (size_t)tc * NB * CAP_;
        return f * sizeof(float) + hs * sizeof(unsigned short) + ii * sizeof(int);
    };
    const int tcnt = (need(2) <= ws_size) ? 2 : 1;

    char* ws = (char*)d_ws;
    float* agg    = (float*)ws;                               // tc*N*6
    float* bstats = agg + (size_t)tcnt * N * IN_;             // tc*gb*72
    float* coef   = bstats + (size_t)tcnt * gb * 2 * DIM_;    // tc*72
    float* emb    = coef + (size_t)tcnt * 2 * DIM_;           // G*72
    unsigned short* zhA = (unsigned short*)(emb + (size_t)G * T_ * DIM_);
    unsigned short* zhB = zhA + (size_t)tcnt * bufN;
    int*   bcnt   = (int*)(zhB + (size_t)tcnt * bufN);        // tc*NB
    int*   rp     = bcnt + (size_t)tcnt * NB;                 // tc*N
    int*   deg    = rp + (size_t)tcnt * N;                    // tc*N
    int*   bbuf   = deg + (size_t)tcnt * N;                   // tc*NB*CAP_

    float* outp = (float*)d_out;

    for (int t0 = 0; t0 < T_; t0 += tcnt) {
        const int tc = tcnt;

        hipMemsetAsync(bcnt, 0, (size_t)tc * NB * sizeof(int), stream);
        binsort_k<<<tc * gbin, 256, 0, stream>>>(ei, t0, gbin, bcnt, bbuf, E, NB);
        csrify_k<<<tc * NB, 256, 0, stream>>>(bcnt, bbuf, rp, deg, N, NB);

        // conv1: fp32 gather of x, MLP, bf16 out -> zhA
        gather_k<IN_><<<dim3((N + 95) / 96, tc), 576, 0, stream>>>(
                x + (size_t)t0 * N * IN_, (size_t)N * IN_,
                rp, deg, bbuf, agg, (size_t)N * IN_, N);
        node6_k<<<dim3(gn, tc), 256, 0, stream>>>(
                agg, (size_t)N * IN_, wA[0], bA[0], wB[0], bB[0], t0,
                zhA, bufN, bstats, gn, N);
        bnfin_k<<<tc, 288, 0, stream>>>(bstats, gn, gb, bng, bnb, t0, 0, coef, inv_n);

        // conv2 fused: zhA -> zhB
        conv36f_k<<<dim3(gb, tc), 576, 0, stream>>>(
                zhA, bufN, rp, deg, bbuf, coef,
                wA[1], bA[1], wB[1], bB[1], t0, zhB, bstats, gb, N);
        bnfin_k<<<tc, 288, 0, stream>>>(bstats, gb, gb, bng, bnb, t0, 1, coef, inv_n);

        // conv3 fused: zhB -> zhA
        conv36f_k<<<dim3(gb, tc), 576, 0, stream>>>(
                zhB, bufN, rp, deg, bbuf, coef,
                wA[2], bA[2], wB[2], bB[2], t0, zhA, bstats, gb, N);
        bnfin_k<<<tc, 288, 0, stream>>>(bstats, gb, gb, bng, bnb, t0, 2, coef, inv_n);

        pool_k<<<dim3(G, tc), 288, 0, stream>>>(zhA, bufN, coef, batch, t0, emb, N);
    }
    head_k<<<G, 64, 0, stream>>>(emb, hw1, hb1, hw2, hb2, hw3, hb3, outp, G);
}

// Round 10
// 505.893 us; speedup vs baseline: 1.5505x; 1.5505x over previous
//
#include <hip/hip_runtime.h>

#define T_   2
#define IN_  6
#define DIM_ 36
#define LIN_ 54
#define OUT_ 18
#define BN_EPS 1e-5f

#define WSH_   7        // bucket width = 128 dst nodes
#define WMSK_  127
#define CAP_   2560     // per-bucket capacity (mean 2046, 11 sigma headroom)
#define TILE_  6144     // edges per binsort block
#define NBMAX_ 1024     // max buckets supported by in-LDS scan

__device__ __forceinline__ unsigned short f2bf(float f) {
    unsigned u = __float_as_uint(f);
    unsigned r = (u + 0x7FFFu + ((u >> 16) & 1u)) >> 16;    // RNE
    return (unsigned short)r;
}
__device__ __forceinline__ float bf2f(unsigned short h) {
    return __uint_as_float(((unsigned)h) << 16);
}
__device__ __forceinline__ unsigned packbf(float a, float b) {
    return (unsigned)f2bf(a) | ((unsigned)f2bf(b) << 16);
}

// ===========================================================================
// binsort_k: bin edges by dst bucket with LDS staging; coalesced packed
// writes (src 17b | dstoff 7b). Grid covers tc transforms: lt = bid/gbin.
// ===========================================================================
__global__ __launch_bounds__(256) void binsort_k(
    const int* __restrict__ ei, int t0, int gbin,
    int* __restrict__ bcnt, int* __restrict__ bbuf, int ne, int nb)
{
    __shared__ int cntl[NBMAX_], cursl[NBMAX_], gbasel[NBMAX_];
    __shared__ int aux[256];
    __shared__ int sortedl[TILE_];

    const int tid  = threadIdx.x;
    const int lt   = blockIdx.x / gbin;
    const int tile = blockIdx.x % gbin;
    const int base = tile * TILE_;
    const int cnt_e = min(TILE_, ne - base);
    const int* srcp = ei + (size_t)(t0 + lt) * 2 * ne;
    const int* dstp = srcp + ne;
    int* bcnt_t = bcnt + (size_t)lt * nb;

    for (int i = tid; i < NBMAX_; i += 256) cntl[i] = 0;
    __syncthreads();

    for (int i = tid; i < cnt_e; i += 256)
        atomicAdd(&cntl[dstp[base + i] >> WSH_], 1);
    __syncthreads();

    int t4 = tid * 4;
    int c0 = cntl[t4+0], c1 = cntl[t4+1], c2 = cntl[t4+2], c3 = cntl[t4+3];
    int lsum = c0 + c1 + c2 + c3;
    aux[tid] = lsum;
    __syncthreads();
    for (int off = 1; off < 256; off <<= 1) {
        int v = (tid >= off) ? aux[tid - off] : 0;
        __syncthreads();
        aux[tid] += v;
        __syncthreads();
    }
    int eb = aux[tid] - lsum;
    cursl[t4+0] = eb;
    cursl[t4+1] = eb + c0;
    cursl[t4+2] = eb + c0 + c1;
    cursl[t4+3] = eb + c0 + c1 + c2;
    __syncthreads();

    for (int b = tid; b < nb; b += 256) {
        int c = cntl[b];
        gbasel[b] = c ? atomicAdd(&bcnt_t[b], c) : 0;
    }
    __syncthreads();

    for (int i = tid; i < cnt_e; i += 256) {
        int s = srcp[base + i], d = dstp[base + i];
        int p = atomicAdd(&cursl[d >> WSH_], 1);
        sortedl[p] = s | ((d & WMSK_) << 17);
    }
    __syncthreads();

    int wv = tid >> 6, ln = tid & 63;
    for (int b = wv; b < nb; b += 4) {
        int c = cntl[b];
        if (!c) continue;
        int lb = cursl[b] - c;
        int gb = gbasel[b];
        size_t ga = ((size_t)lt * nb + b) * CAP_ + gb;
        for (int i = ln; i < c; i += 64)
            if (gb + i < CAP_) bbuf[ga + i] = sortedl[lb + i];
    }
}

// ===========================================================================
// csrify_k: one block per (t,bucket): sort bucket by dst node in LDS, write
// back coalesced (unpacked src), emit rp (global into bbuf) and deg.
// ===========================================================================
__global__ __launch_bounds__(256) void csrify_k(
    const int* __restrict__ bcnt, int* __restrict__ bbuf,
    int* __restrict__ rp, int* __restrict__ deg, int n, int nb)
{
    __shared__ int ent[CAP_], srt[CAP_];
    __shared__ int cnt[128], cur[128], sc[128];
    const int b = blockIdx.x, tid = threadIdx.x;
    const int blocal = b % nb, lt = b / nb;
    int c = min(bcnt[b], CAP_);
    int* seg = bbuf + (size_t)b * CAP_;

    for (int i = tid; i < c; i += 256) ent[i] = seg[i];
    if (tid < 128) cnt[tid] = 0;
    __syncthreads();
    for (int i = tid; i < c; i += 256)
        atomicAdd(&cnt[(ent[i] >> 17) & WMSK_], 1);
    __syncthreads();
    if (tid < 128) sc[tid] = cnt[tid];
    __syncthreads();
    for (int off = 1; off < 128; off <<= 1) {
        int v = (tid >= off && tid < 128) ? sc[tid - off] : 0;
        __syncthreads();
        if (tid < 128) sc[tid] += v;
        __syncthreads();
    }
    int node0 = blocal << WSH_;
    if (tid < 128) {
        int excl = sc[tid] - cnt[tid];
        cur[tid] = excl;
        if (node0 + tid < n) {
            rp[(size_t)lt * n + node0 + tid]  = b * CAP_ + excl;
            deg[(size_t)lt * n + node0 + tid] = cnt[tid];
        }
    }
    __syncthreads();
    for (int i = tid; i < c; i += 256) {
        int v = ent[i];
        int p = atomicAdd(&cur[(v >> 17) & WMSK_], 1);
        srt[p] = v & 0x1FFFF;
    }
    __syncthreads();
    for (int i = tid; i < c; i += 256) seg[i] = srt[i];
}

// ===========================================================================
// gather_k (conv1, D=6, fp32): agg[i] = x[i] + sum_{nbr} x[nbr].
// ===========================================================================
template<int D>
__global__ __launch_bounds__(576) void gather_k(
        const float* __restrict__ hbase, size_t hstride,
        const int* __restrict__ rp, const int* __restrict__ deg,
        const int* __restrict__ csr, float* __restrict__ agg,
        size_t astride, int n)
{
    const int NPB = 576 / D;
    const int slot = blockIdx.y;
    const float* h = hbase + (size_t)slot * hstride;
    int g = blockIdx.x * NPB + threadIdx.x / D;
    int lane = threadIdx.x % D;
    if (g >= n) return;
    int lo = rp[(size_t)slot * n + g], hi = lo + deg[(size_t)slot * n + g];
    float a0 = h[(size_t)g * D + lane], a1 = 0.f, a2 = 0.f, a3 = 0.f;
    int e = lo;
    for (; e + 3 < hi; e += 4) {
        int s0 = csr[e], s1 = csr[e + 1], s2 = csr[e + 2], s3 = csr[e + 3];
        a0 += h[(size_t)s0 * D + lane];
        a1 += h[(size_t)s1 * D + lane];
        a2 += h[(size_t)s2 * D + lane];
        a3 += h[(size_t)s3 * D + lane];
    }
    for (; e < hi; ++e) a0 += h[(size_t)csr[e] * D + lane];
    agg[(size_t)slot * astride + (size_t)g * D + lane] = (a0 + a1) + (a2 + a3);
}

// ===========================================================================
// gather36h_k: bf16 rows, 9 lanes/node (4 features/lane via uint2 = 8B/lane).
// agg[i] = self + sum_nbr, fp32 out. Barrier-free, register accumulation.
// 576 threads = 64 nodes/block.
// ===========================================================================
__global__ __launch_bounds__(576) void gather36h_k(
        const unsigned short* __restrict__ zh, size_t zhstride,
        const int* __restrict__ rp, const int* __restrict__ deg,
        const int* __restrict__ csr, float* __restrict__ agg,
        size_t astride, int n)
{
    const int slot = blockIdx.y;
    const unsigned short* zhs = zh + (size_t)slot * zhstride;
    int g = blockIdx.x * 64 + threadIdx.x / 9;
    int lane = threadIdx.x % 9;                  // features 4*lane .. 4*lane+3
    if (g >= n) return;
    size_t off = (size_t)slot * n + g;
    int lo = rp[off], hi = lo + deg[off];

    uint2 v = *reinterpret_cast<const uint2*>(zhs + (size_t)g * DIM_ + 4 * lane);
    float a0 = bf2f((unsigned short)(v.x & 0xffff));
    float a1 = bf2f((unsigned short)(v.x >> 16));
    float a2 = bf2f((unsigned short)(v.y & 0xffff));
    float a3 = bf2f((unsigned short)(v.y >> 16));
    float b0 = 0.f, b1 = 0.f, b2 = 0.f, b3 = 0.f;

    int e = lo;
    for (; e + 1 < hi; e += 2) {
        int s0 = csr[e], s1 = csr[e + 1];
        uint2 u0 = *reinterpret_cast<const uint2*>(zhs + (size_t)s0 * DIM_ + 4 * lane);
        uint2 u1 = *reinterpret_cast<const uint2*>(zhs + (size_t)s1 * DIM_ + 4 * lane);
        a0 += bf2f((unsigned short)(u0.x & 0xffff));
        a1 += bf2f((unsigned short)(u0.x >> 16));
        a2 += bf2f((unsigned short)(u0.y & 0xffff));
        a3 += bf2f((unsigned short)(u0.y >> 16));
        b0 += bf2f((unsigned short)(u1.x & 0xffff));
        b1 += bf2f((unsigned short)(u1.x >> 16));
        b2 += bf2f((unsigned short)(u1.y & 0xffff));
        b3 += bf2f((unsigned short)(u1.y >> 16));
    }
    if (e < hi) {
        uint2 u0 = *reinterpret_cast<const uint2*>(zhs + (size_t)csr[e] * DIM_ + 4 * lane);
        a0 += bf2f((unsigned short)(u0.x & 0xffff));
        a1 += bf2f((unsigned short)(u0.x >> 16));
        a2 += bf2f((unsigned short)(u0.y & 0xffff));
        a3 += bf2f((unsigned short)(u0.y >> 16));
    }
    float4 r; r.x = a0 + b0; r.y = a1 + b1; r.z = a2 + b2; r.w = a3 + b3;
    *reinterpret_cast<float4*>(agg + (size_t)slot * astride + (size_t)g * DIM_ + 4 * lane) = r;
}

// ===========================================================================
// node6_k (conv1 MLP): hin = agg; y = relu(Wa hin+ba); out = relu(Wb y+bb);
// bf16 z out; per-block BN stat row. Weights via wave-uniform s_load.
// ===========================================================================
__global__ __launch_bounds__(256) void node6_k(
    const float* __restrict__ agg, size_t astride,
    const float* __restrict__ wAb, const float* __restrict__ bAb,
    const float* __restrict__ wBb, const float* __restrict__ bBb,
    int t0,
    unsigned short* __restrict__ zho, size_t zstride,
    float* __restrict__ bstats, int gn, int n)
{
    __shared__ float sstat[4][2 * DIM_];
    const int slot = blockIdx.y;
    const int t = t0 + slot;
    const float* wa = wAb + (size_t)t * DIM_ * IN_;
    const float* ba = bAb + (size_t)t * DIM_;
    const float* wb = wBb + (size_t)t * DIM_ * DIM_;
    const float* bb = bBb + (size_t)t * DIM_;

    int node = blockIdx.x * 256 + threadIdx.x;
    bool active = node < n;

    float hin[IN_];
    if (active) {
        const float2* ar2 = reinterpret_cast<const float2*>(
                agg + (size_t)slot * astride + (size_t)node * IN_);
        float2 v0 = ar2[0], v1 = ar2[1], v2 = ar2[2];
        hin[0] = v0.x; hin[1] = v0.y; hin[2] = v1.x;
        hin[3] = v1.y; hin[4] = v2.x; hin[5] = v2.y;
    } else {
        #pragma unroll
        for (int k = 0; k < IN_; ++k) hin[k] = 0.f;
    }

    float y[DIM_];
    #pragma unroll
    for (int j = 0; j < DIM_; ++j) {
        float acc = ba[j];
        #pragma unroll
        for (int k = 0; k < IN_; ++k) acc = fmaf(wa[j * IN_ + k], hin[k], acc);
        y[j] = fmaxf(acc, 0.f);
    }
    float out[DIM_];
    #pragma unroll
    for (int j = 0; j < DIM_; ++j) {
        float acc = bb[j];
        #pragma unroll
        for (int k = 0; k < DIM_; ++k) acc = fmaf(wb[j * DIM_ + k], y[k], acc);
        out[j] = active ? fmaxf(acc, 0.f) : 0.f;
    }

    if (active) {
        unsigned* zr = reinterpret_cast<unsigned*>(
                zho + (size_t)slot * zstride + (size_t)node * DIM_);
        #pragma unroll
        for (int j = 0; j < DIM_ / 2; ++j) zr[j] = packbf(out[2*j], out[2*j+1]);
    }

    int wid = threadIdx.x >> 6, lane = threadIdx.x & 63;
    #pragma unroll
    for (int j = 0; j < DIM_; ++j) {
        float s = out[j], sq = out[j] * out[j];
        for (int off = 32; off; off >>= 1) {
            s  += __shfl_down(s,  off);
            sq += __shfl_down(sq, off);
        }
        if (lane == 0) { sstat[wid][j] = s; sstat[wid][DIM_ + j] = sq; }
    }
    __syncthreads();
    if (threadIdx.x < 2 * DIM_) {
        float s = sstat[0][threadIdx.x] + sstat[1][threadIdx.x]
                + sstat[2][threadIdx.x] + sstat[3][threadIdx.x];
        bstats[((size_t)slot * gn + blockIdx.x) * (2 * DIM_) + threadIdx.x] = s;
    }
}

// ===========================================================================
// node36_k (convs 2,3 MLP): hin = a.agg + (1+deg).b2 (agg already = h+S);
// y = relu(Wa hin+ba); out = relu(Wb y+bb); bf16 z out; stat row per block.
// ===========================================================================
__global__ __launch_bounds__(256) void node36_k(
    const float* __restrict__ agg, size_t astride,
    const int* __restrict__ deg,
    const float* __restrict__ coef,
    const float* __restrict__ wAb, const float* __restrict__ bAb,
    const float* __restrict__ wBb, const float* __restrict__ bBb,
    int t0,
    unsigned short* __restrict__ zho, size_t zstride,
    float* __restrict__ bstats, int gn, int n)
{
    __shared__ float sstat[4][2 * DIM_];
    const int slot = blockIdx.y;
    const int t = t0 + slot;
    const float* wa = wAb + (size_t)t * DIM_ * DIM_;
    const float* ba = bAb + (size_t)t * DIM_;
    const float* wb = wBb + (size_t)t * DIM_ * DIM_;
    const float* bb = bBb + (size_t)t * DIM_;
    const float* ca  = coef + (size_t)slot * 2 * DIM_;
    const float* cb2 = ca + DIM_;

    int node = blockIdx.x * 256 + threadIdx.x;
    bool active = node < n;

    float hin[DIM_];
    if (active) {
        const float4* ar4 = reinterpret_cast<const float4*>(
                agg + (size_t)slot * astride + (size_t)node * DIM_);
        #pragma unroll
        for (int q = 0; q < 9; ++q) {
            float4 av = ar4[q];
            hin[4*q+0] = av.x; hin[4*q+1] = av.y;
            hin[4*q+2] = av.z; hin[4*q+3] = av.w;
        }
        float ds = 1.0f + (float)deg[(size_t)slot * n + node];
        #pragma unroll
        for (int k = 0; k < DIM_; ++k)
            hin[k] = ca[k] * hin[k] + ds * cb2[k];
    } else {
        #pragma unroll
        for (int k = 0; k < DIM_; ++k) hin[k] = 0.f;
    }

    float y[DIM_];
    #pragma unroll
    for (int j = 0; j < DIM_; ++j) {
        float acc = ba[j];
        #pragma unroll
        for (int k = 0; k < DIM_; ++k) acc = fmaf(wa[j * DIM_ + k], hin[k], acc);
        y[j] = fmaxf(acc, 0.f);
    }
    float out[DIM_];
    #pragma unroll
    for (int j = 0; j < DIM_; ++j) {
        float acc = bb[j];
        #pragma unroll
        for (int k = 0; k < DIM_; ++k) acc = fmaf(wb[j * DIM_ + k], y[k], acc);
        out[j] = active ? fmaxf(acc, 0.f) : 0.f;
    }

    if (active) {
        unsigned* zr = reinterpret_cast<unsigned*>(
                zho + (size_t)slot * zstride + (size_t)node * DIM_);
        #pragma unroll
        for (int j = 0; j < DIM_ / 2; ++j) zr[j] = packbf(out[2*j], out[2*j+1]);
    }

    int wid = threadIdx.x >> 6, lane = threadIdx.x & 63;
    #pragma unroll
    for (int j = 0; j < DIM_; ++j) {
        float s = out[j], sq = out[j] * out[j];
        for (int off = 32; off; off >>= 1) {
            s  += __shfl_down(s,  off);
            sq += __shfl_down(sq, off);
        }
        if (lane == 0) { sstat[wid][j] = s; sstat[wid][DIM_ + j] = sq; }
    }
    __syncthreads();
    if (threadIdx.x < 2 * DIM_) {
        float s = sstat[0][threadIdx.x] + sstat[1][threadIdx.x]
                + sstat[2][threadIdx.x] + sstat[3][threadIdx.x];
        bstats[((size_t)slot * gn + blockIdx.x) * (2 * DIM_) + threadIdx.x] = s;
    }
}

// ===========================================================================
// bnfin_k: reduce nrows stat rows -> fused affine coef {a, b2}. Grid (tc).
// ===========================================================================
__global__ __launch_bounds__(288) void bnfin_k(
    const float* __restrict__ bstats, int nrows, int rstride,
    const float* __restrict__ bng, const float* __restrict__ bnb,
    int t0, int c, float* __restrict__ coef, float inv_n)
{
    __shared__ float part[4][2 * DIM_];
    const int slot = blockIdx.x;
    const int t = t0 + slot;
    int tid = threadIdx.x;
    int col = tid % (2 * DIM_), quarter = tid / (2 * DIM_);
    const float* bs = bstats + (size_t)slot * rstride * (2 * DIM_);
    float s = 0.f;
    for (int i = quarter; i < nrows; i += 4) s += bs[(size_t)i * (2 * DIM_) + col];
    part[quarter][col] = s;
    __syncthreads();
    if (tid < 2 * DIM_)
        part[0][tid] = part[0][tid] + part[1][tid] + part[2][tid] + part[3][tid];
    __syncthreads();
    if (tid < DIM_) {
        float mean = part[0][tid] * inv_n;
        float var  = part[0][DIM_ + tid] * inv_n - mean * mean;
        float aa   = bng[((size_t)t * 3 + c) * DIM_ + tid] / sqrtf(var + BN_EPS);
        coef[(size_t)slot * 2 * DIM_ + tid]        = aa;
        coef[(size_t)slot * 2 * DIM_ + DIM_ + tid] = bnb[((size_t)t * 3 + c) * DIM_ + tid] - aa * mean;
    }
}

// ===========================================================================
// pool_k: per-graph mean pool over bf16 z (batch sorted), conv-3 coef.
// 288 threads = 16 row-groups x 18 feature-pairs (uint loads).
// ===========================================================================
__global__ __launch_bounds__(288) void pool_k(
    const unsigned short* __restrict__ zh, size_t zstride,
    const float* __restrict__ coef,
    const int* __restrict__ batch, int t0,
    float* __restrict__ emb, int n)
{
    __shared__ int slo, shi;
    __shared__ float sp0[16][19], sp1[16][19];
    const int slot = blockIdx.y;
    const int t = t0 + slot;
    const int* bt = batch + (size_t)t * n;
    const unsigned short* zt = zh + (size_t)slot * zstride;
    const float* ca  = coef + (size_t)slot * 2 * DIM_;
    const float* cb2 = ca + DIM_;

    int g = blockIdx.x;
    int tid = threadIdx.x;
    if (tid == 0) {
        int lo = 0, hi = n;
        while (lo < hi) { int m = (lo + hi) >> 1; if (bt[m] < g) lo = m + 1; else hi = m; }
        slo = lo;
        int lo2 = lo, hi2 = n;
        while (lo2 < hi2) { int m = (lo2 + hi2) >> 1; if (bt[m] < g + 1) lo2 = m + 1; else hi2 = m; }
        shi = lo2;
    }
    __syncthreads();
    int lo = slo, hi = shi;
    int fp = tid % 18, j = tid / 18;    // feature pair, row group
    float acc0 = 0.f, acc1 = 0.f;
    for (int i = lo + j; i < hi; i += 16) {
        unsigned v = *reinterpret_cast<const unsigned*>(zt + (size_t)i * DIM_ + 2 * fp);
        acc0 += bf2f((unsigned short)(v & 0xffff));
        acc1 += bf2f((unsigned short)(v >> 16));
    }
    sp0[j][fp] = acc0;
    sp1[j][fp] = acc1;
    __syncthreads();
    if (tid < DIM_) {
        int f = tid, fpair = f >> 1, hi_ = f & 1;
        float s = 0.f;
        #pragma unroll
        for (int jj = 0; jj < 16; ++jj)
            s += hi_ ? sp1[jj][fpair] : sp0[jj][fpair];
        int cnt = hi - lo;
        float val = 0.f;
        if (cnt > 0) val = ca[f] * (s / (float)cnt) + cb2[f];
        emb[(size_t)g * (T_ * DIM_) + t * DIM_ + f] = val;
    }
}

// ===========================================================================
// head_k: one 64-thread block per graph, layers staged through LDS.
// ===========================================================================
__global__ __launch_bounds__(64) void head_k(
    const float* __restrict__ emb,
    const float* __restrict__ hw1, const float* __restrict__ hb1,
    const float* __restrict__ hw2, const float* __restrict__ hb2,
    const float* __restrict__ hw3, const float* __restrict__ hb3,
    float* __restrict__ out, int ng)
{
    const int EMB = T_ * DIM_;
    int g = blockIdx.x;
    if (g >= ng) return;
    __shared__ float se[EMB], st1[LIN_], st2[OUT_];
    int tid = threadIdx.x;
    for (int i = tid; i < EMB; i += 64) se[i] = emb[(size_t)g * EMB + i];
    __syncthreads();
    if (tid < LIN_) {
        float acc = hb1[tid];
        #pragma unroll
        for (int k = 0; k < EMB; ++k) acc = fmaf(hw1[tid * EMB + k], se[k], acc);
        st1[tid] = fmaxf(acc, 0.f);
    }
    __syncthreads();
    if (tid < OUT_) {
        float acc = hb2[tid];
        #pragma unroll
        for (int k = 0; k < LIN_; ++k) acc = fmaf(hw2[tid * LIN_ + k], st1[k], acc);
        st2[tid] = fmaxf(acc, 0.f);
    }
    __syncthreads();
    if (tid == 0) {
        float acc = hb3[0];
        #pragma unroll
        for (int k = 0; k < OUT_; ++k) acc = fmaf(hw3[k], st2[k], acc);
        out[g] = 1.f / (1.f + expf(-acc));
    }
}

// ===========================================================================
extern "C" void kernel_launch(void* const* d_in, const int* in_sizes, int n_in,
                              void* d_out, int out_size, void* d_ws, size_t ws_size,
                              hipStream_t stream)
{
    const float* x     = (const float*)d_in[0];
    const int*   ei    = (const int*)d_in[1];
    const int*   batch = (const int*)d_in[2];
    const float* wA[3] = {(const float*)d_in[3], (const float*)d_in[7], (const float*)d_in[11]};
    const float* bA[3] = {(const float*)d_in[4], (const float*)d_in[8], (const float*)d_in[12]};
    const float* wB[3] = {(const float*)d_in[5], (const float*)d_in[9], (const float*)d_in[13]};
    const float* bB[3] = {(const float*)d_in[6], (const float*)d_in[10], (const float*)d_in[14]};
    const float* bng = (const float*)d_in[15];
    const float* bnb = (const float*)d_in[16];
    const float* hw1 = (const float*)d_in[17];
    const float* hb1 = (const float*)d_in[18];
    const float* hw2 = (const float*)d_in[19];
    const float* hb2 = (const float*)d_in[20];
    const float* hw3 = (const float*)d_in[21];
    const float* hb3 = (const float*)d_in[22];

    const int N = in_sizes[2] / T_;
    const int E = in_sizes[1] / (2 * T_);
    const int G = out_size;
    const int NB = (N + WMSK_) / 128;
    const int gn = (N + 255) / 256;
    const float inv_n = 1.0f / (float)N;
    const int gbin = (E + TILE_ - 1) / TILE_;

    const size_t bufN = (size_t)N * DIM_;
    auto need = [&](int tc) -> size_t {
        size_t f = (size_t)tc * bufN                           // agg fp32
                 + (size_t)tc * gn * 2 * DIM_                  // bstats
                 + (size_t)tc * 2 * DIM_                       // coef
                 + (size_t)G * T_ * DIM_;                      // emb
        size_t hs = 2 * (size_t)tc * bufN;                     // zhA + zhB
        size_t ii = (size_t)tc * NB + 2 * (size_t)tc * N + (size_t)tc * NB * CAP_;
        return f * sizeof(float) + hs * sizeof(unsigned short) + ii * sizeof(int);
    };
    const int tcnt = (need(2) <= ws_size) ? 2 : 1;

    char* ws = (char*)d_ws;
    float* agg    = (float*)ws;                               // tc*N*36 fp32
    float* bstats = agg + (size_t)tcnt * bufN;                // tc*gn*72
    float* coef   = bstats + (size_t)tcnt * gn * 2 * DIM_;    // tc*72
    float* emb    = coef + (size_t)tcnt * 2 * DIM_;           // G*72
    unsigned short* zhA = (unsigned short*)(emb + (size_t)G * T_ * DIM_);
    unsigned short* zhB = zhA + (size_t)tcnt * bufN;
    int*   bcnt   = (int*)(zhB + (size_t)tcnt * bufN);        // tc*NB
    int*   rp     = bcnt + (size_t)tcnt * NB;                 // tc*N
    int*   deg    = rp + (size_t)tcnt * N;                    // tc*N
    int*   bbuf   = deg + (size_t)tcnt * N;                   // tc*NB*CAP_

    float* outp = (float*)d_out;

    for (int t0 = 0; t0 < T_; t0 += tcnt) {
        const int tc = tcnt;

        hipMemsetAsync(bcnt, 0, (size_t)tc * NB * sizeof(int), stream);
        binsort_k<<<tc * gbin, 256, 0, stream>>>(ei, t0, gbin, bcnt, bbuf, E, NB);
        csrify_k<<<tc * NB, 256, 0, stream>>>(bcnt, bbuf, rp, deg, N, NB);

        // conv1: fp32 gather of x (self folded), MLP -> bf16 zhA
        gather_k<IN_><<<dim3((N + 95) / 96, tc), 576, 0, stream>>>(
                x + (size_t)t0 * N * IN_, (size_t)N * IN_,
                rp, deg, bbuf, agg, (size_t)N * IN_, N);
        node6_k<<<dim3(gn, tc), 256, 0, stream>>>(
                agg, (size_t)N * IN_, wA[0], bA[0], wB[0], bB[0], t0,
                zhA, bufN, bstats, gn, N);
        bnfin_k<<<tc, 288, 0, stream>>>(bstats, gn, gn, bng, bnb, t0, 0, coef, inv_n);

        // conv2: bf16 gather zhA -> fp32 agg; MLP -> bf16 zhB
        gather36h_k<<<dim3((N + 63) / 64, tc), 576, 0, stream>>>(
                zhA, bufN, rp, deg, bbuf, agg, bufN, N);
        node36_k<<<dim3(gn, tc), 256, 0, stream>>>(
                agg, bufN, deg, coef, wA[1], bA[1], wB[1], bB[1], t0,
                zhB, bufN, bstats, gn, N);
        bnfin_k<<<tc, 288, 0, stream>>>(bstats, gn, gn, bng, bnb, t0, 1, coef, inv_n);

        // conv3: bf16 gather zhB -> fp32 agg; MLP -> bf16 zhA
        gather36h_k<<<dim3((N + 63) / 64, tc), 576, 0, stream>>>(
                zhB, bufN, rp, deg, bbuf, agg, bufN, N);
        node36_k<<<dim3(gn, tc), 256, 0, stream>>>(
                agg, bufN, deg, coef, wA[2], bA[2], wB[2], bB[2], t0,
                zhA, bufN, bstats, gn, N);
        bnfin_k<<<tc, 288, 0, stream>>>(bstats, gn, gn, bng, bnb, t0, 2, coef, inv_n);

        pool_k<<<dim3(G, tc), 288, 0, stream>>>(zhA, bufN, coef, batch, t0, emb, N);
    }
    head_k<<<G, 64, 0, stream>>>(emb, hw1, hb1, hw2, hb2, hw3, hb3, outp, G);
}